// Round 4
// baseline (109.219 us; speedup 1.0000x reference)
//
#include <hip/hip_runtime.h>
#include <math.h>

#define T_TOK 4096
#define DD 64
#define NHEADS 64          // B*H = 4*16
#define SEG 512            // tokens per landmark segment
#define NCHUNK 32          // 128-token chunks per head
#define CHUNK 128
#define SCALE 0.125f

// workspace layout (in floats)
#define QL_OFF   0                      // [64][8][64]
#define KL_OFF   32768                  // [64][8][64]
#define K2_OFF   65536                  // [64][8][8]
#define CS_OFF   69632                  // [64][8]
#define PINV_OFF 70144                  // [64][8][8]
#define LPQ_OFF  74240                  // [8192][64] per-wave q partials
#define LPK_OFF  598528                 // [8192][64] per-wave k partials
#define PA_OFF   74240                  // [64][32][8][64] (aliases LPQ/LPK after prep)
#define PD_OFF   1122816                // [64][32][8]
#define W2_OFF   1139200                // [64][8][64] pinv @ k3v
// end = 1171968 floats ~= 4.47 MB

// ---------------------------------------------------------------------------
// 1. q & k landmark partials, register+shfl, no barriers.
//    Block = 128 tokens; wave = 32 tokens; lane l: dims 4*(l&15), group l>>4.
// ---------------------------------------------------------------------------
__global__ __launch_bounds__(256) void sum12_kernel(
    const float* __restrict__ q, const float* __restrict__ k,
    float* __restrict__ ws) {
  int tid = threadIdx.x;
  int w = tid >> 6, lane = tid & 63;
  size_t base4 = (size_t)blockIdx.x * 2048 + (size_t)w * 512;  // float4 units
  const float4* q4 = (const float4*)q + base4;
  const float4* k4 = (const float4*)k + base4;
  float4 aq = make_float4(0.f, 0.f, 0.f, 0.f);
  float4 ak = make_float4(0.f, 0.f, 0.f, 0.f);
#pragma unroll
  for (int it = 0; it < 8; ++it) {
    float4 x = q4[it * 64 + lane];
    aq.x += x.x; aq.y += x.y; aq.z += x.z; aq.w += x.w;
    float4 y = k4[it * 64 + lane];
    ak.x += y.x; ak.y += y.y; ak.z += y.z; ak.w += y.w;
  }
#pragma unroll
  for (int s = 16; s <= 32; s <<= 1) {
    aq.x += __shfl_xor(aq.x, s, 64); aq.y += __shfl_xor(aq.y, s, 64);
    aq.z += __shfl_xor(aq.z, s, 64); aq.w += __shfl_xor(aq.w, s, 64);
    ak.x += __shfl_xor(ak.x, s, 64); ak.y += __shfl_xor(ak.y, s, 64);
    ak.z += __shfl_xor(ak.z, s, 64); ak.w += __shfl_xor(ak.w, s, 64);
  }
  if (lane < 16) {
    size_t gw = (size_t)blockIdx.x * 4 + w;
    ((float4*)(ws + LPQ_OFF))[gw * 16 + lane] = aq;
    ((float4*)(ws + LPK_OFF))[gw * 16 + lane] = ak;
  }
}

// ---------------------------------------------------------------------------
// 2. Reduce partials -> q_l,k_l; kernel_2 softmax + column sums.
// ---------------------------------------------------------------------------
__global__ __launch_bounds__(512) void prep_kernel(float* __restrict__ ws) {
  int hb = blockIdx.x, tid = threadIdx.x;
  __shared__ float qls[8][68];
  __shared__ float kls[8][68];
  __shared__ float ee[8][9];
  int m = tid >> 6, d = tid & 63;
  float sq = 0.f, sk = 0.f;
#pragma unroll
  for (int c = 0; c < 16; ++c) {
    size_t idx = (size_t)(hb * 128 + m * 16 + c) * 64 + d;
    sq += ws[LPQ_OFF + idx];
    sk += ws[LPK_OFF + idx];
  }
  sq *= (1.f / (float)SEG);
  sk *= (1.f / (float)SEG);
  qls[m][d] = sq;
  kls[m][d] = sk;
  ws[QL_OFF + hb * 512 + tid] = sq;
  ws[KL_OFF + hb * 512 + tid] = sk;
  __syncthreads();
  if (tid < 64) {
    int i = tid >> 3, j = tid & 7;
    float dot = 0.f;
#pragma unroll
    for (int dd = 0; dd < 64; ++dd) dot += qls[i][dd] * kls[j][dd];
    ee[i][j] = __expf(dot * SCALE);   // logits tiny: shift-free softmax safe
  }
  __syncthreads();
  if (tid < 64) {
    int i = tid >> 3, j = tid & 7;
    float ssum = 0.f;
#pragma unroll
    for (int jj = 0; jj < 8; ++jj) ssum += ee[i][jj];
    ws[K2_OFF + hb * 64 + tid] = ee[i][j] / ssum;
  }
  if (tid < 8) {
    float cs = 0.f;
    for (int ii = 0; ii < 8; ++ii) {
      float ssum = 0.f;
#pragma unroll
      for (int jj = 0; jj < 8; ++jj) ssum += ee[ii][jj];
      cs += ee[ii][tid] / ssum;
    }
    ws[CS_OFF + hb * 8 + tid] = cs;
  }
}

// ---------------------------------------------------------------------------
// 3. Newton-Schulz pseudo-inverse (global max over all 512 column sums).
// ---------------------------------------------------------------------------
__global__ __launch_bounds__(64) void pinv_kernel(float* __restrict__ ws) {
  int hb = blockIdx.x;
  int tid = threadIdx.x;
  float mx = 0.f;
  for (int t = 0; t < 8; ++t) mx = fmaxf(mx, ws[CS_OFF + t * 64 + tid]);
  for (int off = 32; off; off >>= 1) mx = fmaxf(mx, __shfl_xor(mx, off, 64));
  float inv = 1.f / mx;

  int i = tid >> 3, j = tid & 7;
  __shared__ float K[8][9], V[8][9], X[8][9], Y[8][9];
  K[i][j] = ws[K2_OFF + hb * 64 + tid];
  V[i][j] = ws[K2_OFF + hb * 64 + j * 8 + i] * inv;  // (1/max) * K^T
  __syncthreads();
  for (int it = 0; it < 6; ++it) {
    float x = 0.f;
    for (int kk = 0; kk < 8; ++kk) x += K[i][kk] * V[kk][j];
    X[i][j] = x;
    __syncthreads();
    float bm = 0.f;
    for (int kk = 0; kk < 8; ++kk) bm += X[i][kk] * X[kk][j];
    bm = 7.f * x - bm;
    Y[i][j] = bm;
    __syncthreads();
    float dm = 0.f;
    for (int kk = 0; kk < 8; ++kk) dm += X[i][kk] * Y[kk][j];
    dm = 15.f * x - dm;
    __syncthreads();
    Y[i][j] = dm;
    __syncthreads();
    float vd = 0.f;
    for (int kk = 0; kk < 8; ++kk) vd += V[i][kk] * Y[kk][j];
    float vn = 0.25f * (13.f * V[i][j] - vd);
    __syncthreads();
    V[i][j] = vn;
    __syncthreads();
  }
  ws[PINV_OFF + hb * 64 + tid] = V[i][j];
}

// ---------------------------------------------------------------------------
// 4. k3v partials: register+shfl, no main-loop barriers.
//    Wave handles 32 tokens; acc[8] float4 + den[8] in registers.
// ---------------------------------------------------------------------------
__global__ __launch_bounds__(256) void k3v_kernel(
    const float* __restrict__ k, const float* __restrict__ v,
    float* __restrict__ ws) {
  int tid = threadIdx.x;
  int w = tid >> 6, lane = tid & 63, q4i = lane & 15;
  int hb = blockIdx.x >> 5, c = blockIdx.x & 31;

  float4 qlf[8];
#pragma unroll
  for (int m = 0; m < 8; ++m)
    qlf[m] = ((const float4*)(ws + QL_OFF))[hb * 128 + m * 16 + q4i];

  size_t base4 = ((size_t)hb * T_TOK + (size_t)c * CHUNK + (size_t)w * 32) * 16;
  const float4* k4 = (const float4*)k + base4;
  const float4* v4 = (const float4*)v + base4;

  float4 acc[8];
  float den[8];
#pragma unroll
  for (int m = 0; m < 8; ++m) {
    acc[m] = make_float4(0.f, 0.f, 0.f, 0.f);
    den[m] = 0.f;
  }

#pragma unroll 2
  for (int it = 0; it < 8; ++it) {
    float4 kk = k4[it * 64 + lane];
    float4 vv = v4[it * 64 + lane];
    float p[8];
#pragma unroll
    for (int m = 0; m < 8; ++m) {
      float dp = kk.x * qlf[m].x + kk.y * qlf[m].y + kk.z * qlf[m].z + kk.w * qlf[m].w;
      dp += __shfl_xor(dp, 1, 64);
      dp += __shfl_xor(dp, 2, 64);
      dp += __shfl_xor(dp, 4, 64);
      dp += __shfl_xor(dp, 8, 64);
      p[m] = __expf(dp * SCALE);
    }
#pragma unroll
    for (int m = 0; m < 8; ++m) {
      acc[m].x += p[m] * vv.x; acc[m].y += p[m] * vv.y;
      acc[m].z += p[m] * vv.z; acc[m].w += p[m] * vv.w;
      den[m] += p[m];
    }
  }
  // cross-group reduce (tokens of groups 0..3)
#pragma unroll
  for (int m = 0; m < 8; ++m) {
#pragma unroll
    for (int s = 16; s <= 32; s <<= 1) {
      acc[m].x += __shfl_xor(acc[m].x, s, 64);
      acc[m].y += __shfl_xor(acc[m].y, s, 64);
      acc[m].z += __shfl_xor(acc[m].z, s, 64);
      acc[m].w += __shfl_xor(acc[m].w, s, 64);
      den[m] += __shfl_xor(den[m], s, 64);
    }
  }
  // block combine: 4 waves -> one [8][64] partial + den[8]
  __shared__ float4 accs[4][8][16];   // 8 KB
  __shared__ float dens[4][8];
  if (lane < 16) {
#pragma unroll
    for (int m = 0; m < 8; ++m) accs[w][m][q4i] = acc[m];
  }
  if (lane == 0) {
#pragma unroll
    for (int m = 0; m < 8; ++m) dens[w][m] = den[m];
  }
  __syncthreads();
  if (tid < 128) {
    int m = tid >> 4, i = tid & 15;
    float4 a = accs[0][m][i], b = accs[1][m][i], cc = accs[2][m][i], dd = accs[3][m][i];
    float4 s = make_float4(a.x + b.x + cc.x + dd.x, a.y + b.y + cc.y + dd.y,
                           a.z + b.z + cc.z + dd.z, a.w + b.w + cc.w + dd.w);
    ((float4*)(ws + PA_OFF))[((size_t)(hb * 32 + c) * 8 + m) * 16 + i] = s;
  }
  if (tid < 8)
    ws[PD_OFF + (hb * 32 + c) * 8 + tid] =
        dens[0][tid] + dens[1][tid] + dens[2][tid] + dens[3][tid];
}

// ---------------------------------------------------------------------------
// 5. Reduce k3v partials, normalize, fold in pinv: W2 = pinv @ k3v.
// ---------------------------------------------------------------------------
__global__ __launch_bounds__(512) void redw2_kernel(float* __restrict__ ws) {
  int hb = blockIdx.x, tid = threadIdx.x;
  __shared__ float k3vs[8][68];
  __shared__ float pv[8][9];
  int m = tid >> 6, d = tid & 63;
  float s = 0.f, den = 0.f;
  for (int c = 0; c < NCHUNK; ++c) {
    s += ws[PA_OFF + (((size_t)hb * NCHUNK + c) * 8 + m) * 64 + d];
    den += ws[PD_OFF + (hb * NCHUNK + c) * 8 + m];
  }
  k3vs[m][d] = s / den;
  if (tid < 64) pv[tid >> 3][tid & 7] = ws[PINV_OFF + hb * 64 + tid];
  __syncthreads();
  float o = 0.f;
#pragma unroll
  for (int j = 0; j < 8; ++j) o += pv[m][j] * k3vs[j][d];
  ws[W2_OFF + hb * 512 + tid] = o;
}

// ---------------------------------------------------------------------------
// 6. Output: register+shfl, no LDS.  p = exp(q.k_l*scale); out = (p/Σp) @ W2.
// ---------------------------------------------------------------------------
__global__ __launch_bounds__(256) void out_kernel(
    const float* __restrict__ q, float* __restrict__ out,
    const float* __restrict__ ws) {
  int tid = threadIdx.x;
  int w = tid >> 6, lane = tid & 63, q4i = lane & 15;
  int hb = blockIdx.x >> 5, c = blockIdx.x & 31;

  float4 klf[8], w2f[8];
#pragma unroll
  for (int m = 0; m < 8; ++m) {
    klf[m] = ((const float4*)(ws + KL_OFF))[hb * 128 + m * 16 + q4i];
    w2f[m] = ((const float4*)(ws + W2_OFF))[hb * 128 + m * 16 + q4i];
  }
  size_t base4 = ((size_t)hb * T_TOK + (size_t)c * CHUNK + (size_t)w * 32) * 16;
  const float4* q4 = (const float4*)q + base4;
  float4* o4 = (float4*)out + base4;

#pragma unroll 2
  for (int it = 0; it < 8; ++it) {
    float4 qq = q4[it * 64 + lane];
    float p[8];
    float s = 0.f;
#pragma unroll
    for (int m = 0; m < 8; ++m) {
      float dp = qq.x * klf[m].x + qq.y * klf[m].y + qq.z * klf[m].z + qq.w * klf[m].w;
      dp += __shfl_xor(dp, 1, 64);
      dp += __shfl_xor(dp, 2, 64);
      dp += __shfl_xor(dp, 4, 64);
      dp += __shfl_xor(dp, 8, 64);
      p[m] = __expf(dp * SCALE);
      s += p[m];
    }
    float inv = 1.f / s;
    float4 o = make_float4(0.f, 0.f, 0.f, 0.f);
#pragma unroll
    for (int m = 0; m < 8; ++m) {
      float wgt = p[m] * inv;
      o.x += wgt * w2f[m].x; o.y += wgt * w2f[m].y;
      o.z += wgt * w2f[m].z; o.w += wgt * w2f[m].w;
    }
    o4[it * 64 + lane] = o;
  }
}

// ---------------------------------------------------------------------------
extern "C" void kernel_launch(void* const* d_in, const int* in_sizes, int n_in,
                              void* d_out, int out_size, void* d_ws, size_t ws_size,
                              hipStream_t stream) {
  const float* q = (const float*)d_in[0];
  const float* k = (const float*)d_in[1];
  const float* v = (const float*)d_in[2];
  float* out = (float*)d_out;
  float* ws = (float*)d_ws;

  sum12_kernel<<<2048, 256, 0, stream>>>(q, k, ws);
  prep_kernel<<<NHEADS, 512, 0, stream>>>(ws);
  pinv_kernel<<<NHEADS, 64, 0, stream>>>(ws);
  k3v_kernel<<<NHEADS * NCHUNK, 256, 0, stream>>>(k, v, ws);
  redw2_kernel<<<NHEADS, 512, 0, stream>>>(ws);
  out_kernel<<<NHEADS * NCHUNK, 256, 0, stream>>>(q, out, ws);
}

// Round 5
// 106.702 us; speedup vs baseline: 1.0236x; 1.0236x over previous
//
#include <hip/hip_runtime.h>
#include <math.h>

#define T_TOK 4096
#define DD 64
#define NHEADS 64          // B*H = 4*16
#define SEG 512            // tokens per landmark segment
#define NCHUNK 32          // 128-token chunks per head
#define CHUNK 128
#define SCALE 0.125f

// workspace layout (in floats)
#define QL_OFF   0                      // [64][8][64]
#define KL_OFF   32768                  // [64][8][64]
#define K2_OFF   65536                  // [64][8][8]
#define CS_OFF   69632                  // [64][8]
#define LPQ_OFF  74240                  // [2048][64] q landmark partials
#define KP_OFF   205312                 // [2048][64] k landmark partials
#define PA_OFF   74240                  // [64][32][8][64]  (aliases LPQ+KP: both
                                        //  dead before vpass writes PA)
#define PD_OFF   1122816                // [64][32][8] denominators (from ppass)
#define W2_OFF   1139200                // [64][8][64] pinv @ k3v
#define P_OFF    1171968                // [64][4096][8] p values (8 MB)
// end = 3269120 floats ~= 13.1 MB

// ---------------------------------------------------------------------------
// 1. q landmark partials: one block per 128 tokens (2048 blocks). Single q stream.
// ---------------------------------------------------------------------------
__global__ __launch_bounds__(256) void qsum_kernel(
    const float* __restrict__ q, float* __restrict__ ws) {
  int tid = threadIdx.x;
  const float4* q4 = (const float4*)q + (size_t)blockIdx.x * 2048;
  float4 a = make_float4(0.f, 0.f, 0.f, 0.f);
#pragma unroll
  for (int it = 0; it < 8; ++it) {
    float4 x = q4[it * 256 + tid];
    a.x += x.x; a.y += x.y; a.z += x.z; a.w += x.w;
  }
  __shared__ float4 red[16][17];
  red[tid >> 4][tid & 15] = a;
  __syncthreads();
  if (tid < 16) {
    float4 s = make_float4(0.f, 0.f, 0.f, 0.f);
#pragma unroll
    for (int g = 0; g < 16; ++g) {
      float4 r = red[g][tid];
      s.x += r.x; s.y += r.y; s.z += r.z; s.w += r.w;
    }
    ((float4*)(ws + LPQ_OFF))[blockIdx.x * 16 + tid] = s;
  }
}

// ---------------------------------------------------------------------------
// 2. Reduce q partials -> q_l.
// ---------------------------------------------------------------------------
__global__ __launch_bounds__(512) void prepq_kernel(float* __restrict__ ws) {
  int hb = blockIdx.x, tid = threadIdx.x;
  int m = tid >> 6, d = tid & 63;
  float s = 0.f;
#pragma unroll
  for (int c2 = 0; c2 < 4; ++c2)
    s += ws[LPQ_OFF + (size_t)(hb * 32 + m * 4 + c2) * 64 + d];
  ws[QL_OFF + hb * 512 + tid] = s * (1.f / (float)SEG);
}

// ---------------------------------------------------------------------------
// 3. ppass: read k (single stream). For each token compute p[m]=exp(q_l.k*scale),
//    write p to ws; accumulate per-chunk denominators and k landmark partials.
//    Block = (head, 128-token chunk); wave = 32 tokens; 16-lane group = 1 token.
// ---------------------------------------------------------------------------
__global__ __launch_bounds__(256) void ppass_kernel(
    const float* __restrict__ k, float* __restrict__ ws) {
  int tid = threadIdx.x;
  int w = tid >> 6, lane = tid & 63, q4i = lane & 15, g = lane >> 4;
  int hb = blockIdx.x >> 5, c = blockIdx.x & 31;

  float4 qlf[8];
#pragma unroll
  for (int m = 0; m < 8; ++m)
    qlf[m] = ((const float4*)(ws + QL_OFF))[hb * 128 + m * 16 + q4i];

  size_t tokbase = (size_t)hb * T_TOK + (size_t)c * CHUNK + (size_t)w * 32;
  const float4* k4 = (const float4*)k + tokbase * 16;

  float4 ksum = make_float4(0.f, 0.f, 0.f, 0.f);
  float den[8];
#pragma unroll
  for (int m = 0; m < 8; ++m) den[m] = 0.f;

#pragma unroll 2
  for (int it = 0; it < 8; ++it) {
    float4 kk = k4[it * 64 + lane];
    ksum.x += kk.x; ksum.y += kk.y; ksum.z += kk.z; ksum.w += kk.w;
    float p[8];
#pragma unroll
    for (int m = 0; m < 8; ++m) {
      float dp = kk.x * qlf[m].x + kk.y * qlf[m].y + kk.z * qlf[m].z + kk.w * qlf[m].w;
      dp += __shfl_xor(dp, 1, 64);
      dp += __shfl_xor(dp, 2, 64);
      dp += __shfl_xor(dp, 4, 64);
      dp += __shfl_xor(dp, 8, 64);
      p[m] = __expf(dp * SCALE);
      den[m] += p[m];
    }
    // lanes 0..7 of each 16-group write p[q4i] (static-index select chain)
    float pw = q4i == 1 ? p[1] : q4i == 2 ? p[2] : q4i == 3 ? p[3] :
               q4i == 4 ? p[4] : q4i == 5 ? p[5] : q4i == 6 ? p[6] :
               q4i == 7 ? p[7] : p[0];
    if (q4i < 8)
      ws[P_OFF + (tokbase + it * 4 + g) * 8 + q4i] = pw;
  }
  // cross-group reduce (4 token-groups -> whole wave's 32 tokens)
#pragma unroll
  for (int m = 0; m < 8; ++m) {
    den[m] += __shfl_xor(den[m], 16, 64);
    den[m] += __shfl_xor(den[m], 32, 64);
  }
#pragma unroll
  for (int s = 16; s <= 32; s <<= 1) {
    ksum.x += __shfl_xor(ksum.x, s, 64); ksum.y += __shfl_xor(ksum.y, s, 64);
    ksum.z += __shfl_xor(ksum.z, s, 64); ksum.w += __shfl_xor(ksum.w, s, 64);
  }
  __shared__ float4 ksums[4][16];
  __shared__ float dens[4][8];
  if (lane < 16) ksums[w][lane] = ksum;
  float dw = q4i == 1 ? den[1] : q4i == 2 ? den[2] : q4i == 3 ? den[3] :
             q4i == 4 ? den[4] : q4i == 5 ? den[5] : q4i == 6 ? den[6] :
             q4i == 7 ? den[7] : den[0];
  if (lane < 8) dens[w][lane] = dw;
  __syncthreads();
  if (tid < 16) {
    float4 a = ksums[0][tid], b = ksums[1][tid], cc = ksums[2][tid], dd = ksums[3][tid];
    float4 s = make_float4(a.x + b.x + cc.x + dd.x, a.y + b.y + cc.y + dd.y,
                           a.z + b.z + cc.z + dd.z, a.w + b.w + cc.w + dd.w);
    ((float4*)(ws + KP_OFF))[(size_t)(hb * 32 + c) * 16 + tid] = s;
  }
  if (tid < 8)
    ws[PD_OFF + (hb * 32 + c) * 8 + tid] =
        dens[0][tid] + dens[1][tid] + dens[2][tid] + dens[3][tid];
}

// ---------------------------------------------------------------------------
// 4. Reduce k partials -> k_l; kernel_2 softmax + column sums.
// ---------------------------------------------------------------------------
__global__ __launch_bounds__(512) void prepk_kernel(float* __restrict__ ws) {
  int hb = blockIdx.x, tid = threadIdx.x;
  __shared__ float qls[8][68];
  __shared__ float kls[8][68];
  __shared__ float ee[8][9];
  int m = tid >> 6, d = tid & 63;
  float s = 0.f;
#pragma unroll
  for (int c2 = 0; c2 < 4; ++c2)
    s += ws[KP_OFF + (size_t)(hb * 32 + m * 4 + c2) * 64 + d];
  s *= (1.f / (float)SEG);
  kls[m][d] = s;
  ws[KL_OFF + hb * 512 + tid] = s;
  qls[m][d] = ws[QL_OFF + hb * 512 + tid];
  __syncthreads();
  if (tid < 64) {
    int i = tid >> 3, j = tid & 7;
    float dot = 0.f;
#pragma unroll
    for (int dd = 0; dd < 64; ++dd) dot += qls[i][dd] * kls[j][dd];
    ee[i][j] = __expf(dot * SCALE);   // logits tiny: shift-free softmax safe
  }
  __syncthreads();
  if (tid < 64) {
    int i = tid >> 3, j = tid & 7;
    float ssum = 0.f;
#pragma unroll
    for (int jj = 0; jj < 8; ++jj) ssum += ee[i][jj];
    ws[K2_OFF + hb * 64 + tid] = ee[i][j] / ssum;
  }
  if (tid < 8) {
    float cs = 0.f;
    for (int ii = 0; ii < 8; ++ii) {
      float ssum = 0.f;
#pragma unroll
      for (int jj = 0; jj < 8; ++jj) ssum += ee[ii][jj];
      cs += ee[ii][tid] / ssum;
    }
    ws[CS_OFF + hb * 8 + tid] = cs;
  }
}

// ---------------------------------------------------------------------------
// 5. vpass: read v (single stream) + small p; accumulate k3v partials.
// ---------------------------------------------------------------------------
__global__ __launch_bounds__(256) void vpass_kernel(
    const float* __restrict__ v, float* __restrict__ ws) {
  int tid = threadIdx.x;
  int w = tid >> 6, lane = tid & 63, g = lane >> 4;
  int hb = blockIdx.x >> 5, c = blockIdx.x & 31;

  size_t tokbase = (size_t)hb * T_TOK + (size_t)c * CHUNK + (size_t)w * 32;
  // stage this wave's 32x8 p-block into LDS (one float4 per lane)
  float4 pf = ((const float4*)(ws + P_OFF))[tokbase * 2 + lane];
  __shared__ float plds[4][260];
  *(float4*)&plds[w][lane * 4] = pf;
  __syncthreads();

  const float4* v4 = (const float4*)v + tokbase * 16;
  float4 acc[8];
#pragma unroll
  for (int m = 0; m < 8; ++m) acc[m] = make_float4(0.f, 0.f, 0.f, 0.f);

#pragma unroll 2
  for (int it = 0; it < 8; ++it) {
    float4 vv = v4[it * 64 + lane];
    int t = it * 4 + g;
    float4 pa = *(const float4*)&plds[w][t * 8];      // p[t][0..3] broadcast
    float4 pb = *(const float4*)&plds[w][t * 8 + 4];  // p[t][4..7]
    acc[0].x += pa.x * vv.x; acc[0].y += pa.x * vv.y; acc[0].z += pa.x * vv.z; acc[0].w += pa.x * vv.w;
    acc[1].x += pa.y * vv.x; acc[1].y += pa.y * vv.y; acc[1].z += pa.y * vv.z; acc[1].w += pa.y * vv.w;
    acc[2].x += pa.z * vv.x; acc[2].y += pa.z * vv.y; acc[2].z += pa.z * vv.z; acc[2].w += pa.z * vv.w;
    acc[3].x += pa.w * vv.x; acc[3].y += pa.w * vv.y; acc[3].z += pa.w * vv.z; acc[3].w += pa.w * vv.w;
    acc[4].x += pb.x * vv.x; acc[4].y += pb.x * vv.y; acc[4].z += pb.x * vv.z; acc[4].w += pb.x * vv.w;
    acc[5].x += pb.y * vv.x; acc[5].y += pb.y * vv.y; acc[5].z += pb.y * vv.z; acc[5].w += pb.y * vv.w;
    acc[6].x += pb.z * vv.x; acc[6].y += pb.z * vv.y; acc[6].z += pb.z * vv.z; acc[6].w += pb.z * vv.w;
    acc[7].x += pb.w * vv.x; acc[7].y += pb.w * vv.y; acc[7].z += pb.w * vv.z; acc[7].w += pb.w * vv.w;
  }
  // cross-group reduce (sum over the wave's 4 token-groups)
#pragma unroll
  for (int m = 0; m < 8; ++m) {
#pragma unroll
    for (int s = 16; s <= 32; s <<= 1) {
      acc[m].x += __shfl_xor(acc[m].x, s, 64);
      acc[m].y += __shfl_xor(acc[m].y, s, 64);
      acc[m].z += __shfl_xor(acc[m].z, s, 64);
      acc[m].w += __shfl_xor(acc[m].w, s, 64);
    }
  }
  __shared__ float4 accs[4][8][17];
  if (lane < 16) {
#pragma unroll
    for (int m = 0; m < 8; ++m) accs[w][m][lane] = acc[m];
  }
  __syncthreads();
  if (tid < 128) {
    int m = tid >> 4, i = tid & 15;
    float4 a = accs[0][m][i], b = accs[1][m][i], cc = accs[2][m][i], dd = accs[3][m][i];
    float4 s = make_float4(a.x + b.x + cc.x + dd.x, a.y + b.y + cc.y + dd.y,
                           a.z + b.z + cc.z + dd.z, a.w + b.w + cc.w + dd.w);
    ((float4*)(ws + PA_OFF))[((size_t)(hb * 32 + c) * 8 + m) * 16 + i] = s;
  }
}

// ---------------------------------------------------------------------------
// 6. pinv (Newton-Schulz, global max over all 512 colsums) fused with
//    k3v reduce + W2 = pinv @ (k3v/den).  One 512-thr block per head.
// ---------------------------------------------------------------------------
__global__ __launch_bounds__(512) void pinvw2_kernel(float* __restrict__ ws) {
  int hb = blockIdx.x, tid = threadIdx.x;
  __shared__ float k3vs[8][68];
  __shared__ float K[8][9], V[8][9], X[8][9], Y[8][9];
  __shared__ float smax;
  int m = tid >> 6, d = tid & 63;
  // reduce k3v partials + denominators
  float s = 0.f, den = 0.f;
  for (int c = 0; c < NCHUNK; ++c) {
    s += ws[PA_OFF + (((size_t)hb * NCHUNK + c) * 8 + m) * 64 + d];
    den += ws[PD_OFF + (hb * NCHUNK + c) * 8 + m];
  }
  k3vs[m][d] = s / den;
  // global max of column sums (positive)
  if (tid < 64) {
    float mx = 0.f;
    for (int t = 0; t < 8; ++t) mx = fmaxf(mx, ws[CS_OFF + t * 64 + tid]);
    for (int off = 32; off; off >>= 1) mx = fmaxf(mx, __shfl_xor(mx, off, 64));
    if (tid == 0) smax = mx;
  }
  int i = (tid >> 3) & 7, j = tid & 7;
  if (tid < 64) {
    K[i][j] = ws[K2_OFF + hb * 64 + tid];
  }
  __syncthreads();
  if (tid < 64) V[i][j] = K[j][i] * (1.f / smax);   // (1/max) * K^T
  __syncthreads();
  for (int it = 0; it < 6; ++it) {
    float x = 0.f;
    if (tid < 64) {
      for (int kk = 0; kk < 8; ++kk) x += K[i][kk] * V[kk][j];
      X[i][j] = x;
    }
    __syncthreads();
    float bm = 0.f;
    if (tid < 64) {
      for (int kk = 0; kk < 8; ++kk) bm += X[i][kk] * X[kk][j];
      bm = 7.f * x - bm;
      Y[i][j] = bm;
    }
    __syncthreads();
    float dm = 0.f;
    if (tid < 64) {
      for (int kk = 0; kk < 8; ++kk) dm += X[i][kk] * Y[kk][j];
      dm = 15.f * x - dm;
    }
    __syncthreads();
    if (tid < 64) Y[i][j] = dm;
    __syncthreads();
    float vd = 0.f;
    if (tid < 64) {
      for (int kk = 0; kk < 8; ++kk) vd += V[i][kk] * Y[kk][j];
      vd = 0.25f * (13.f * V[i][j] - vd);
    }
    __syncthreads();
    if (tid < 64) V[i][j] = vd;
    __syncthreads();
  }
  // W2 = pinv @ k3vn
  float o = 0.f;
#pragma unroll
  for (int jj = 0; jj < 8; ++jj) o += V[m][jj] * k3vs[jj][d];
  ws[W2_OFF + hb * 512 + tid] = o;
}

// ---------------------------------------------------------------------------
// 7. Output: per 64-token tile: p = exp(q_t . k_l * scale); out = (p/Σp) @ W2.
//    Single q read stream + out write stream.
// ---------------------------------------------------------------------------
#define PADT 68
__global__ __launch_bounds__(256) void out_kernel(
    const float* __restrict__ q, float* __restrict__ out,
    const float* __restrict__ ws) {
  int hb = blockIdx.x >> 6, tt = blockIdx.x & 63;
  int tid = threadIdx.x;
  __shared__ float qt[64][PADT];
  __shared__ float klh[8][68];
  __shared__ float w2s[8][68];
  __shared__ float pl[64][9];

  if (tid < 128) {
    float4 x = ((const float4*)(ws + KL_OFF))[hb * 128 + tid];
    *(float4*)&klh[tid >> 4][(tid & 15) * 4] = x;
    float4 y = ((const float4*)(ws + W2_OFF))[hb * 128 + tid];
    *(float4*)&w2s[tid >> 4][(tid & 15) * 4] = y;
  }
  size_t base4 = ((size_t)hb * T_TOK + (size_t)tt * 64) * 16;
  const float4* q4 = (const float4*)q + base4;
#pragma unroll
  for (int it = 0; it < 4; ++it) {
    int f4 = it * 256 + tid;
    float4 x = q4[f4];
    *(float4*)&qt[f4 >> 4][(f4 & 15) * 4] = x;
  }
  __syncthreads();
#pragma unroll
  for (int p = 0; p < 2; ++p) {
    int idx = p * 256 + tid;
    int t = idx >> 3, m = idx & 7;
    const float4* qr = (const float4*)&qt[t][0];
    const float4* kr = (const float4*)&klh[m][0];
    float dot = 0.f;
#pragma unroll
    for (int d4 = 0; d4 < 16; ++d4) {
      float4 a = qr[d4], b = kr[d4];
      dot += a.x * b.x + a.y * b.y + a.z * b.z + a.w * b.w;
    }
    pl[t][m] = __expf(dot * SCALE);   // logits tiny: no max needed
  }
  __syncthreads();
  float4* o4 = (float4*)out + base4;
#pragma unroll
  for (int i = 0; i < 4; ++i) {
    int t = i * 16 + (tid >> 4);
    int qd = tid & 15;
    float p0 = pl[t][0], p1 = pl[t][1], p2 = pl[t][2], p3 = pl[t][3];
    float p4 = pl[t][4], p5 = pl[t][5], p6 = pl[t][6], p7 = pl[t][7];
    float inv = 1.f / (p0 + p1 + p2 + p3 + p4 + p5 + p6 + p7);
    float4 acc = make_float4(0.f, 0.f, 0.f, 0.f);
    float pm[8] = {p0, p1, p2, p3, p4, p5, p6, p7};
#pragma unroll
    for (int m2 = 0; m2 < 8; ++m2) {
      float w = pm[m2] * inv;
      float4 wv = *(const float4*)&w2s[m2][qd * 4];
      acc.x += w * wv.x; acc.y += w * wv.y; acc.z += w * wv.z; acc.w += w * wv.w;
    }
    o4[i * 256 + tid] = acc;   // wave-contiguous 1 KB stores
  }
}

// ---------------------------------------------------------------------------
extern "C" void kernel_launch(void* const* d_in, const int* in_sizes, int n_in,
                              void* d_out, int out_size, void* d_ws, size_t ws_size,
                              hipStream_t stream) {
  const float* q = (const float*)d_in[0];
  const float* k = (const float*)d_in[1];
  const float* v = (const float*)d_in[2];
  float* out = (float*)d_out;
  float* ws = (float*)d_ws;

  qsum_kernel<<<2048, 256, 0, stream>>>(q, ws);
  prepq_kernel<<<NHEADS, 512, 0, stream>>>(ws);
  ppass_kernel<<<NHEADS * NCHUNK, 256, 0, stream>>>(k, ws);
  prepk_kernel<<<NHEADS, 512, 0, stream>>>(ws);
  vpass_kernel<<<NHEADS * NCHUNK, 256, 0, stream>>>(v, ws);
  pinvw2_kernel<<<NHEADS, 512, 0, stream>>>(ws);
  out_kernel<<<NHEADS * 64, 256, 0, stream>>>(q, out, ws);
}

// Round 6
// 104.419 us; speedup vs baseline: 1.0460x; 1.0219x over previous
//
#include <hip/hip_runtime.h>
#include <math.h>

#define T_TOK 4096
#define DD 64
#define NHEADS 64          // B*H = 4*16
#define SEG 512            // tokens per landmark segment
#define NCHUNK 32          // 128-token chunks per head
#define CHUNK 128
#define SCALE 0.125f

// workspace layout (in floats)
#define QL_OFF   0                      // [64][8][64]
#define KL_OFF   32768                  // [64][8][64]
#define K2_OFF   65536                  // [64][8][8]
#define CS_OFF   69632                  // [64][8]
#define LPQ_OFF  74240                  // [2048][64] q landmark partials
#define KP_OFF   205312                 // [2048][64] k landmark partials
#define PA_OFF   74240                  // [64][32][8][64]  (aliases LPQ+KP: both
                                        //  dead before vpass writes PA)
#define PD_OFF   1122816                // [64][32][8] denominators (from vpass)
#define W2_OFF   1139200                // [64][8][64] pinv @ k3v
#define P_OFF    1171968                // [64][4096][8] p values (8 MB)
// end = 3269120 floats ~= 13.1 MB

// ---------------------------------------------------------------------------
// 1. q landmark partials: one block per 128 tokens (2048 blocks).
//    8 independent hoisted loads per thread.
// ---------------------------------------------------------------------------
__global__ __launch_bounds__(256) void qsum_kernel(
    const float* __restrict__ q, float* __restrict__ ws) {
  int tid = threadIdx.x;
  const float4* q4 = (const float4*)q + (size_t)blockIdx.x * 2048;
  float4 x[8];
#pragma unroll
  for (int it = 0; it < 8; ++it) x[it] = q4[it * 256 + tid];
  float4 a = make_float4(0.f, 0.f, 0.f, 0.f);
#pragma unroll
  for (int it = 0; it < 8; ++it) {
    a.x += x[it].x; a.y += x[it].y; a.z += x[it].z; a.w += x[it].w;
  }
  __shared__ float4 red[16][17];
  red[tid >> 4][tid & 15] = a;
  __syncthreads();
  if (tid < 16) {
    float4 s = make_float4(0.f, 0.f, 0.f, 0.f);
#pragma unroll
    for (int g = 0; g < 16; ++g) {
      float4 r = red[g][tid];
      s.x += r.x; s.y += r.y; s.z += r.z; s.w += r.w;
    }
    ((float4*)(ws + LPQ_OFF))[blockIdx.x * 16 + tid] = s;
  }
}

// ---------------------------------------------------------------------------
// 2. Reduce q partials -> q_l.
// ---------------------------------------------------------------------------
__global__ __launch_bounds__(512) void prepq_kernel(float* __restrict__ ws) {
  int hb = blockIdx.x, tid = threadIdx.x;
  int m = tid >> 6, d = tid & 63;
  float s = 0.f;
#pragma unroll
  for (int c2 = 0; c2 < 4; ++c2)
    s += ws[LPQ_OFF + (size_t)(hb * 32 + m * 4 + c2) * 64 + d];
  ws[QL_OFF + hb * 512 + tid] = s * (1.f / (float)SEG);
}

// ---------------------------------------------------------------------------
// 3. ppass: read k once. p[t][m]=exp(q_l[m].k[t]*scale) via thread-local dots
//    (8 threads per token, m fixed per thread, q_l row in registers, k tile in
//    LDS with conflict-free [128][68] layout).  Also k landmark partials.
// ---------------------------------------------------------------------------
__global__ __launch_bounds__(256) void ppass_kernel(
    const float* __restrict__ k, float* __restrict__ ws) {
  int tid = threadIdx.x;
  int hb = blockIdx.x >> 5, c = blockIdx.x & 31;
  __shared__ float kt[128][68];
  __shared__ float4 red[16][17];

  size_t tokbase = (size_t)hb * T_TOK + (size_t)c * CHUNK;
  const float4* k4 = (const float4*)k + tokbase * 16;
  // hoisted k loads (8 independent)
  float4 kk[8];
#pragma unroll
  for (int it = 0; it < 8; ++it) kk[it] = k4[it * 256 + tid];
  // q_l row for this thread's fixed m (small, L2-resident)
  int m = tid & 7;
  float4 qlrow[16];
#pragma unroll
  for (int d4 = 0; d4 < 16; ++d4)
    qlrow[d4] = ((const float4*)(ws + QL_OFF))[hb * 128 + m * 16 + d4];
  // stage + k landmark partial (thread covers tokens it*16+(tid>>4), dims (tid&15)*4)
  float4 ks = make_float4(0.f, 0.f, 0.f, 0.f);
#pragma unroll
  for (int it = 0; it < 8; ++it) {
    int f4 = it * 256 + tid;
    *(float4*)&kt[f4 >> 4][(f4 & 15) * 4] = kk[it];
    ks.x += kk[it].x; ks.y += kk[it].y; ks.z += kk[it].z; ks.w += kk[it].w;
  }
  red[tid >> 4][tid & 15] = ks;
  __syncthreads();
  if (tid < 16) {
    float4 s = make_float4(0.f, 0.f, 0.f, 0.f);
#pragma unroll
    for (int g = 0; g < 16; ++g) {
      float4 r = red[g][tid];
      s.x += r.x; s.y += r.y; s.z += r.z; s.w += r.w;
    }
    ((float4*)(ws + KP_OFF))[(size_t)(hb * 32 + c) * 16 + tid] = s;
  }
  // dot phase: thread -> (t = rep*32 + tid>>3, m = tid&7); kt reads conflict-free
#pragma unroll
  for (int rep = 0; rep < 4; ++rep) {
    int t = rep * 32 + (tid >> 3);
    const float4* kr = (const float4*)&kt[t][0];
    float dp = 0.f;
#pragma unroll
    for (int d4 = 0; d4 < 16; ++d4) {
      float4 kv = kr[d4];
      dp += kv.x * qlrow[d4].x + kv.y * qlrow[d4].y +
            kv.z * qlrow[d4].z + kv.w * qlrow[d4].w;
    }
    ws[P_OFF + (tokbase + t) * 8 + m] = __expf(dp * SCALE);  // coalesced
  }
}

// ---------------------------------------------------------------------------
// 4. Reduce k partials -> k_l; kernel_2 softmax + column sums.
// ---------------------------------------------------------------------------
__global__ __launch_bounds__(512) void prepk_kernel(float* __restrict__ ws) {
  int hb = blockIdx.x, tid = threadIdx.x;
  __shared__ float qls[8][68];
  __shared__ float kls[8][68];
  __shared__ float ee[8][9];
  int m = tid >> 6, d = tid & 63;
  float s = 0.f;
#pragma unroll
  for (int c2 = 0; c2 < 4; ++c2)
    s += ws[KP_OFF + (size_t)(hb * 32 + m * 4 + c2) * 64 + d];
  s *= (1.f / (float)SEG);
  kls[m][d] = s;
  ws[KL_OFF + hb * 512 + tid] = s;
  qls[m][d] = ws[QL_OFF + hb * 512 + tid];
  __syncthreads();
  if (tid < 64) {
    int i = tid >> 3, j = tid & 7;
    float dot = 0.f;
#pragma unroll
    for (int dd = 0; dd < 64; ++dd) dot += qls[i][dd] * kls[j][dd];
    ee[i][j] = __expf(dot * SCALE);   // logits tiny: shift-free softmax safe
  }
  __syncthreads();
  if (tid < 64) {
    int i = tid >> 3, j = tid & 7;
    float ssum = 0.f;
#pragma unroll
    for (int jj = 0; jj < 8; ++jj) ssum += ee[i][jj];
    ws[K2_OFF + hb * 64 + tid] = ee[i][j] / ssum;
  }
  if (tid < 8) {
    float cs = 0.f;
    for (int ii = 0; ii < 8; ++ii) {
      float ssum = 0.f;
#pragma unroll
      for (int jj = 0; jj < 8; ++jj) ssum += ee[ii][jj];
      cs += ee[ii][tid] / ssum;
    }
    ws[CS_OFF + hb * 8 + tid] = cs;
  }
}

// ---------------------------------------------------------------------------
// 5. vpass: read v (hoisted loads) + p; accumulate k3v partials AND the
//    per-chunk denominators (free: p is already in LDS).
// ---------------------------------------------------------------------------
__global__ __launch_bounds__(256) void vpass_kernel(
    const float* __restrict__ v, float* __restrict__ ws) {
  int tid = threadIdx.x;
  int w = tid >> 6, lane = tid & 63, g = lane >> 4;
  int hb = blockIdx.x >> 5, c = blockIdx.x & 31;

  size_t tokbase = (size_t)hb * T_TOK + (size_t)c * CHUNK + (size_t)w * 32;
  // issue p load first, then the 8 v loads (so the LDS write only waits on p)
  float4 pf = ((const float4*)(ws + P_OFF))[tokbase * 2 + lane];
  const float4* v4 = (const float4*)v + tokbase * 16;
  float4 vv[8];
#pragma unroll
  for (int it = 0; it < 8; ++it) vv[it] = v4[it * 64 + lane];

  __shared__ float plds[4][260];
  *(float4*)&plds[w][lane * 4] = pf;
  __syncthreads();

  float4 acc[8];
#pragma unroll
  for (int m = 0; m < 8; ++m) acc[m] = make_float4(0.f, 0.f, 0.f, 0.f);

#pragma unroll
  for (int it = 0; it < 8; ++it) {
    int t = it * 4 + g;
    float4 pa = *(const float4*)&plds[w][t * 8];      // p[t][0..3] broadcast
    float4 pb = *(const float4*)&plds[w][t * 8 + 4];  // p[t][4..7]
    acc[0].x += pa.x * vv[it].x; acc[0].y += pa.x * vv[it].y; acc[0].z += pa.x * vv[it].z; acc[0].w += pa.x * vv[it].w;
    acc[1].x += pa.y * vv[it].x; acc[1].y += pa.y * vv[it].y; acc[1].z += pa.y * vv[it].z; acc[1].w += pa.y * vv[it].w;
    acc[2].x += pa.z * vv[it].x; acc[2].y += pa.z * vv[it].y; acc[2].z += pa.z * vv[it].z; acc[2].w += pa.z * vv[it].w;
    acc[3].x += pa.w * vv[it].x; acc[3].y += pa.w * vv[it].y; acc[3].z += pa.w * vv[it].z; acc[3].w += pa.w * vv[it].w;
    acc[4].x += pb.x * vv[it].x; acc[4].y += pb.x * vv[it].y; acc[4].z += pb.x * vv[it].z; acc[4].w += pb.x * vv[it].w;
    acc[5].x += pb.y * vv[it].x; acc[5].y += pb.y * vv[it].y; acc[5].z += pb.y * vv[it].z; acc[5].w += pb.y * vv[it].w;
    acc[6].x += pb.z * vv[it].x; acc[6].y += pb.z * vv[it].y; acc[6].z += pb.z * vv[it].z; acc[6].w += pb.z * vv[it].w;
    acc[7].x += pb.w * vv[it].x; acc[7].y += pb.w * vv[it].y; acc[7].z += pb.w * vv[it].z; acc[7].w += pb.w * vv[it].w;
  }
  // cross-group reduce (sum over the wave's 4 token-groups)
#pragma unroll
  for (int m = 0; m < 8; ++m) {
#pragma unroll
    for (int s = 16; s <= 32; s <<= 1) {
      acc[m].x += __shfl_xor(acc[m].x, s, 64);
      acc[m].y += __shfl_xor(acc[m].y, s, 64);
      acc[m].z += __shfl_xor(acc[m].z, s, 64);
      acc[m].w += __shfl_xor(acc[m].w, s, 64);
    }
  }
  __shared__ float4 accs[4][8][17];
  __shared__ float dens[4][8];
  if (lane < 16) {
#pragma unroll
    for (int m = 0; m < 8; ++m) accs[w][m][lane] = acc[m];
  }
  if (lane < 8) {   // denominator for m=lane over this wave's 32 tokens
    float dsum = 0.f;
#pragma unroll
    for (int t = 0; t < 32; ++t) dsum += plds[w][t * 8 + lane];
    dens[w][lane] = dsum;
  }
  __syncthreads();
  if (tid < 128) {
    int m = tid >> 4, i = tid & 15;
    float4 a = accs[0][m][i], b = accs[1][m][i], cc = accs[2][m][i], dd = accs[3][m][i];
    float4 s = make_float4(a.x + b.x + cc.x + dd.x, a.y + b.y + cc.y + dd.y,
                           a.z + b.z + cc.z + dd.z, a.w + b.w + cc.w + dd.w);
    ((float4*)(ws + PA_OFF))[((size_t)(hb * 32 + c) * 8 + m) * 16 + i] = s;
  }
  if (tid < 8)
    ws[PD_OFF + (hb * NCHUNK + c) * 8 + tid] =
        dens[0][tid] + dens[1][tid] + dens[2][tid] + dens[3][tid];
}

// ---------------------------------------------------------------------------
// 6. pinv (Newton-Schulz, global max over all 512 colsums) fused with
//    k3v reduce + W2 = pinv @ (k3v/den).  One 512-thr block per head.
// ---------------------------------------------------------------------------
__global__ __launch_bounds__(512) void pinvw2_kernel(float* __restrict__ ws) {
  int hb = blockIdx.x, tid = threadIdx.x;
  __shared__ float k3vs[8][68];
  __shared__ float K[8][9], V[8][9], X[8][9], Y[8][9];
  __shared__ float smax;
  int m = tid >> 6, d = tid & 63;
  float s = 0.f, den = 0.f;
  for (int c = 0; c < NCHUNK; ++c) {
    s += ws[PA_OFF + (((size_t)hb * NCHUNK + c) * 8 + m) * 64 + d];
    den += ws[PD_OFF + (hb * NCHUNK + c) * 8 + m];
  }
  k3vs[m][d] = s / den;
  if (tid < 64) {
    float mx = 0.f;
    for (int t = 0; t < 8; ++t) mx = fmaxf(mx, ws[CS_OFF + t * 64 + tid]);
    for (int off = 32; off; off >>= 1) mx = fmaxf(mx, __shfl_xor(mx, off, 64));
    if (tid == 0) smax = mx;
  }
  int i = (tid >> 3) & 7, j = tid & 7;
  if (tid < 64) K[i][j] = ws[K2_OFF + hb * 64 + tid];
  __syncthreads();
  if (tid < 64) V[i][j] = K[j][i] * (1.f / smax);   // (1/max) * K^T
  __syncthreads();
  for (int it = 0; it < 6; ++it) {
    float x = 0.f;
    if (tid < 64) {
      for (int kk = 0; kk < 8; ++kk) x += K[i][kk] * V[kk][j];
      X[i][j] = x;
    }
    __syncthreads();
    float bm = 0.f;
    if (tid < 64) {
      for (int kk = 0; kk < 8; ++kk) bm += X[i][kk] * X[kk][j];
      bm = 7.f * x - bm;
      Y[i][j] = bm;
    }
    __syncthreads();
    float dm = 0.f;
    if (tid < 64) {
      for (int kk = 0; kk < 8; ++kk) dm += X[i][kk] * Y[kk][j];
      dm = 15.f * x - dm;
    }
    __syncthreads();
    if (tid < 64) Y[i][j] = dm;
    __syncthreads();
    float vd = 0.f;
    if (tid < 64) {
      for (int kk = 0; kk < 8; ++kk) vd += V[i][kk] * Y[kk][j];
      vd = 0.25f * (13.f * V[i][j] - vd);
    }
    __syncthreads();
    if (tid < 64) V[i][j] = vd;
    __syncthreads();
  }
  float o = 0.f;
#pragma unroll
  for (int jj = 0; jj < 8; ++jj) o += V[m][jj] * k3vs[jj][d];
  ws[W2_OFF + hb * 512 + tid] = o;
}

// ---------------------------------------------------------------------------
// 7. Output: per 64-token tile: p = exp(q_t . k_l * scale); out = (p/Σp) @ W2.
//    k_l row held in registers (m fixed per thread); q loads hoisted.
// ---------------------------------------------------------------------------
__global__ __launch_bounds__(256) void out_kernel(
    const float* __restrict__ q, float* __restrict__ out,
    const float* __restrict__ ws) {
  int hb = blockIdx.x >> 6, tt = blockIdx.x & 63;
  int tid = threadIdx.x;
  __shared__ float qt[64][68];
  __shared__ float w2s[8][68];
  __shared__ float pl[64][9];

  size_t base4 = ((size_t)hb * T_TOK + (size_t)tt * 64) * 16;
  const float4* q4 = (const float4*)q + base4;
  float4 qq[4];
#pragma unroll
  for (int it = 0; it < 4; ++it) qq[it] = q4[it * 256 + tid];
  // k_l row for this thread's fixed m (small, L2-resident)
  int m = tid & 7;
  float4 klrow[16];
#pragma unroll
  for (int d4 = 0; d4 < 16; ++d4)
    klrow[d4] = ((const float4*)(ws + KL_OFF))[hb * 128 + m * 16 + d4];
  if (tid < 128) {
    float4 y = ((const float4*)(ws + W2_OFF))[hb * 128 + tid];
    *(float4*)&w2s[tid >> 4][(tid & 15) * 4] = y;
  }
#pragma unroll
  for (int it = 0; it < 4; ++it) {
    int f4 = it * 256 + tid;
    *(float4*)&qt[f4 >> 4][(f4 & 15) * 4] = qq[it];
  }
  __syncthreads();
#pragma unroll
  for (int rep = 0; rep < 2; ++rep) {
    int t = rep * 32 + (tid >> 3);
    const float4* qr = (const float4*)&qt[t][0];
    float dot = 0.f;
#pragma unroll
    for (int d4 = 0; d4 < 16; ++d4) {
      float4 a = qr[d4];
      dot += a.x * klrow[d4].x + a.y * klrow[d4].y +
             a.z * klrow[d4].z + a.w * klrow[d4].w;
    }
    pl[t][m] = __expf(dot * SCALE);   // logits tiny: no max needed
  }
  __syncthreads();
  float4* o4 = (float4*)out + base4;
#pragma unroll
  for (int i = 0; i < 4; ++i) {
    int t = i * 16 + (tid >> 4);
    int qd = tid & 15;
    float p0 = pl[t][0], p1 = pl[t][1], p2 = pl[t][2], p3 = pl[t][3];
    float p4 = pl[t][4], p5 = pl[t][5], p6 = pl[t][6], p7 = pl[t][7];
    float inv = 1.f / (p0 + p1 + p2 + p3 + p4 + p5 + p6 + p7);
    float4 acc = make_float4(0.f, 0.f, 0.f, 0.f);
    float pm[8] = {p0, p1, p2, p3, p4, p5, p6, p7};
#pragma unroll
    for (int m2 = 0; m2 < 8; ++m2) {
      float w = pm[m2] * inv;
      float4 wv = *(const float4*)&w2s[m2][qd * 4];
      acc.x += w * wv.x; acc.y += w * wv.y; acc.z += w * wv.z; acc.w += w * wv.w;
    }
    o4[i * 256 + tid] = acc;   // wave-contiguous 1 KB stores
  }
}

// ---------------------------------------------------------------------------
extern "C" void kernel_launch(void* const* d_in, const int* in_sizes, int n_in,
                              void* d_out, int out_size, void* d_ws, size_t ws_size,
                              hipStream_t stream) {
  const float* q = (const float*)d_in[0];
  const float* k = (const float*)d_in[1];
  const float* v = (const float*)d_in[2];
  float* out = (float*)d_out;
  float* ws = (float*)d_ws;

  qsum_kernel<<<2048, 256, 0, stream>>>(q, ws);
  prepq_kernel<<<NHEADS, 512, 0, stream>>>(ws);
  ppass_kernel<<<NHEADS * NCHUNK, 256, 0, stream>>>(k, ws);
  prepk_kernel<<<NHEADS, 512, 0, stream>>>(ws);
  vpass_kernel<<<NHEADS * NCHUNK, 256, 0, stream>>>(v, ws);
  pinvw2_kernel<<<NHEADS, 512, 0, stream>>>(ws);
  out_kernel<<<NHEADS * 64, 256, 0, stream>>>(q, out, ws);
}

// Round 7
// 101.712 us; speedup vs baseline: 1.0738x; 1.0266x over previous
//
#include <hip/hip_runtime.h>
#include <math.h>

#define T_TOK 4096
#define DD 64
#define NHEADS 64          // B*H = 4*16
#define SEG 512            // tokens per landmark segment
#define NCHUNK 32          // 128-token chunks per head (vpass granularity)
#define CHUNK 128
#define SCALE 0.125f

// workspace layout (in floats)
#define QL_OFF   0                      // [64][8][64]
#define KL_OFF   32768                  // [64][8][64]
#define K2_OFF   65536                  // [64][8][8]
#define CS_OFF   69632                  // [64][8]
#define KP_OFF   205312                 // [1024][64] k landmark partials (256-tok chunks)
#define PA_OFF   74240                  // [64][32][8][64]  (aliases KP: KP dead after prepk)
#define PD_OFF   1122816                // [64][32][8] denominators (from vpass)
#define W2_OFF   1139200                // [64][8][64] pinv @ k3v
#define P_OFF    1171968                // [64][4096][8] p values (8 MB)
// end = 3269120 floats ~= 13.1 MB

// ---------------------------------------------------------------------------
// 1. q landmarks: one block per (head, landmark) 512-token segment (512 blocks).
//    Register double-buffered 8-load batches; writes q_l directly.
// ---------------------------------------------------------------------------
__global__ __launch_bounds__(256) void qsum_kernel(
    const float* __restrict__ q, float* __restrict__ ws) {
  int tid = threadIdx.x;
  const float4* q4 = (const float4*)q + (size_t)blockIdx.x * 8192;
  float4 b[2][8];
#pragma unroll
  for (int i = 0; i < 8; ++i) b[0][i] = q4[i * 256 + tid];
  float4 a = make_float4(0.f, 0.f, 0.f, 0.f);
#pragma unroll
  for (int j = 0; j < 4; ++j) {
    if (j < 3) {
#pragma unroll
      for (int i = 0; i < 8; ++i)
        b[(j + 1) & 1][i] = q4[(j + 1) * 2048 + i * 256 + tid];
    }
#pragma unroll
    for (int i = 0; i < 8; ++i) {
      float4 x = b[j & 1][i];
      a.x += x.x; a.y += x.y; a.z += x.z; a.w += x.w;
    }
  }
  __shared__ float4 red[16][17];
  red[tid >> 4][tid & 15] = a;
  __syncthreads();
  if (tid < 16) {
    float4 s = make_float4(0.f, 0.f, 0.f, 0.f);
#pragma unroll
    for (int g = 0; g < 16; ++g) {
      float4 r = red[g][tid];
      s.x += r.x; s.y += r.y; s.z += r.z; s.w += r.w;
    }
    const float inv = 1.f / (float)SEG;
    s.x *= inv; s.y *= inv; s.z *= inv; s.w *= inv;
    ((float4*)(ws + QL_OFF))[blockIdx.x * 16 + tid] = s;   // q_l directly
  }
}

// ---------------------------------------------------------------------------
// 2. ppass: one block per 256-token chunk (1024 blocks), two 128-token tiles.
//    Tile-B loads issued before tile-A's dot phase (in flight across barrier).
//    p[t][m]=exp(q_l[m].k[t]*scale) via thread-local dots (8 thr/token,
//    m fixed per thread, q_l row in registers).  Also k landmark partials.
// ---------------------------------------------------------------------------
__global__ __launch_bounds__(256) void ppass_kernel(
    const float* __restrict__ k, float* __restrict__ ws) {
  int tid = threadIdx.x;
  int hb = blockIdx.x >> 4, c = blockIdx.x & 15;
  __shared__ float kt[128][68];
  __shared__ float4 red[16][17];

  size_t tokbase = (size_t)hb * T_TOK + (size_t)c * 256;
  const float4* k4 = (const float4*)k + tokbase * 16;
  // tile A loads
  float4 kkA[8];
#pragma unroll
  for (int i = 0; i < 8; ++i) kkA[i] = k4[i * 256 + tid];
  // q_l row for this thread's fixed m (small, L2-resident)
  int m = tid & 7;
  float4 qlrow[16];
#pragma unroll
  for (int d4 = 0; d4 < 16; ++d4)
    qlrow[d4] = ((const float4*)(ws + QL_OFF))[hb * 128 + m * 16 + d4];
  // stage A + ksum
  float4 ks = make_float4(0.f, 0.f, 0.f, 0.f);
#pragma unroll
  for (int it = 0; it < 8; ++it) {
    int f4 = it * 256 + tid;
    *(float4*)&kt[f4 >> 4][(f4 & 15) * 4] = kkA[it];
    ks.x += kkA[it].x; ks.y += kkA[it].y; ks.z += kkA[it].z; ks.w += kkA[it].w;
  }
  // issue tile B loads now (in flight across barrier + dots A)
  float4 kkB[8];
#pragma unroll
  for (int i = 0; i < 8; ++i) kkB[i] = k4[2048 + i * 256 + tid];
  __syncthreads();
  // dots A
#pragma unroll
  for (int rep = 0; rep < 4; ++rep) {
    int t = rep * 32 + (tid >> 3);
    const float4* kr = (const float4*)&kt[t][0];
    float dp = 0.f;
#pragma unroll
    for (int d4 = 0; d4 < 16; ++d4) {
      float4 kv = kr[d4];
      dp += kv.x * qlrow[d4].x + kv.y * qlrow[d4].y +
            kv.z * qlrow[d4].z + kv.w * qlrow[d4].w;
    }
    ws[P_OFF + (tokbase + t) * 8 + m] = __expf(dp * SCALE);
  }
  __syncthreads();
  // stage B + ksum
#pragma unroll
  for (int it = 0; it < 8; ++it) {
    int f4 = it * 256 + tid;
    *(float4*)&kt[f4 >> 4][(f4 & 15) * 4] = kkB[it];
    ks.x += kkB[it].x; ks.y += kkB[it].y; ks.z += kkB[it].z; ks.w += kkB[it].w;
  }
  red[tid >> 4][tid & 15] = ks;
  __syncthreads();
  if (tid < 16) {   // k landmark partial for this 256-token chunk
    float4 s = make_float4(0.f, 0.f, 0.f, 0.f);
#pragma unroll
    for (int g = 0; g < 16; ++g) {
      float4 r = red[g][tid];
      s.x += r.x; s.y += r.y; s.z += r.z; s.w += r.w;
    }
    ((float4*)(ws + KP_OFF))[blockIdx.x * 16 + tid] = s;
  }
  // dots B
#pragma unroll
  for (int rep = 0; rep < 4; ++rep) {
    int t = rep * 32 + (tid >> 3);
    const float4* kr = (const float4*)&kt[t][0];
    float dp = 0.f;
#pragma unroll
    for (int d4 = 0; d4 < 16; ++d4) {
      float4 kv = kr[d4];
      dp += kv.x * qlrow[d4].x + kv.y * qlrow[d4].y +
            kv.z * qlrow[d4].z + kv.w * qlrow[d4].w;
    }
    ws[P_OFF + (tokbase + 128 + t) * 8 + m] = __expf(dp * SCALE);
  }
}

// ---------------------------------------------------------------------------
// 3. Reduce k partials -> k_l; kernel_2 softmax + column sums.
// ---------------------------------------------------------------------------
__global__ __launch_bounds__(512) void prepk_kernel(float* __restrict__ ws) {
  int hb = blockIdx.x, tid = threadIdx.x;
  __shared__ float qls[8][68];
  __shared__ float kls[8][68];
  __shared__ float ee[8][9];
  int m = tid >> 6, d = tid & 63;
  float s = ws[KP_OFF + (size_t)(hb * 16 + 2 * m) * 64 + d] +
            ws[KP_OFF + (size_t)(hb * 16 + 2 * m + 1) * 64 + d];
  s *= (1.f / (float)SEG);
  kls[m][d] = s;
  ws[KL_OFF + hb * 512 + tid] = s;
  qls[m][d] = ws[QL_OFF + hb * 512 + tid];
  __syncthreads();
  if (tid < 64) {
    int i = tid >> 3, j = tid & 7;
    float dot = 0.f;
#pragma unroll
    for (int dd = 0; dd < 64; ++dd) dot += qls[i][dd] * kls[j][dd];
    ee[i][j] = __expf(dot * SCALE);   // logits tiny: shift-free softmax safe
  }
  __syncthreads();
  if (tid < 64) {
    int i = tid >> 3, j = tid & 7;
    float ssum = 0.f;
#pragma unroll
    for (int jj = 0; jj < 8; ++jj) ssum += ee[i][jj];
    ws[K2_OFF + hb * 64 + tid] = ee[i][j] / ssum;
  }
  if (tid < 8) {
    float cs = 0.f;
    for (int ii = 0; ii < 8; ++ii) {
      float ssum = 0.f;
#pragma unroll
      for (int jj = 0; jj < 8; ++jj) ssum += ee[ii][jj];
      cs += ee[ii][tid] / ssum;
    }
    ws[CS_OFF + hb * 8 + tid] = cs;
  }
}

// ---------------------------------------------------------------------------
// 4. vpass: read v (hoisted loads) + p; accumulate k3v partials AND the
//    per-chunk denominators.
// ---------------------------------------------------------------------------
__global__ __launch_bounds__(256) void vpass_kernel(
    const float* __restrict__ v, float* __restrict__ ws) {
  int tid = threadIdx.x;
  int w = tid >> 6, lane = tid & 63, g = lane >> 4;
  int hb = blockIdx.x >> 5, c = blockIdx.x & 31;

  size_t tokbase = (size_t)hb * T_TOK + (size_t)c * CHUNK + (size_t)w * 32;
  float4 pf = ((const float4*)(ws + P_OFF))[tokbase * 2 + lane];
  const float4* v4 = (const float4*)v + tokbase * 16;
  float4 vv[8];
#pragma unroll
  for (int it = 0; it < 8; ++it) vv[it] = v4[it * 64 + lane];

  __shared__ float plds[4][260];
  *(float4*)&plds[w][lane * 4] = pf;
  __syncthreads();

  float4 acc[8];
#pragma unroll
  for (int m = 0; m < 8; ++m) acc[m] = make_float4(0.f, 0.f, 0.f, 0.f);

#pragma unroll
  for (int it = 0; it < 8; ++it) {
    int t = it * 4 + g;
    float4 pa = *(const float4*)&plds[w][t * 8];
    float4 pb = *(const float4*)&plds[w][t * 8 + 4];
    acc[0].x += pa.x * vv[it].x; acc[0].y += pa.x * vv[it].y; acc[0].z += pa.x * vv[it].z; acc[0].w += pa.x * vv[it].w;
    acc[1].x += pa.y * vv[it].x; acc[1].y += pa.y * vv[it].y; acc[1].z += pa.y * vv[it].z; acc[1].w += pa.y * vv[it].w;
    acc[2].x += pa.z * vv[it].x; acc[2].y += pa.z * vv[it].y; acc[2].z += pa.z * vv[it].z; acc[2].w += pa.z * vv[it].w;
    acc[3].x += pa.w * vv[it].x; acc[3].y += pa.w * vv[it].y; acc[3].z += pa.w * vv[it].z; acc[3].w += pa.w * vv[it].w;
    acc[4].x += pb.x * vv[it].x; acc[4].y += pb.x * vv[it].y; acc[4].z += pb.x * vv[it].z; acc[4].w += pb.x * vv[it].w;
    acc[5].x += pb.y * vv[it].x; acc[5].y += pb.y * vv[it].y; acc[5].z += pb.y * vv[it].z; acc[5].w += pb.y * vv[it].w;
    acc[6].x += pb.z * vv[it].x; acc[6].y += pb.z * vv[it].y; acc[6].z += pb.z * vv[it].z; acc[6].w += pb.z * vv[it].w;
    acc[7].x += pb.w * vv[it].x; acc[7].y += pb.w * vv[it].y; acc[7].z += pb.w * vv[it].z; acc[7].w += pb.w * vv[it].w;
  }
#pragma unroll
  for (int m = 0; m < 8; ++m) {
#pragma unroll
    for (int s = 16; s <= 32; s <<= 1) {
      acc[m].x += __shfl_xor(acc[m].x, s, 64);
      acc[m].y += __shfl_xor(acc[m].y, s, 64);
      acc[m].z += __shfl_xor(acc[m].z, s, 64);
      acc[m].w += __shfl_xor(acc[m].w, s, 64);
    }
  }
  __shared__ float4 accs[4][8][17];
  __shared__ float dens[4][8];
  if (lane < 16) {
#pragma unroll
    for (int m = 0; m < 8; ++m) accs[w][m][lane] = acc[m];
  }
  if (lane < 8) {
    float dsum = 0.f;
#pragma unroll
    for (int t = 0; t < 32; ++t) dsum += plds[w][t * 8 + lane];
    dens[w][lane] = dsum;
  }
  __syncthreads();
  if (tid < 128) {
    int m = tid >> 4, i = tid & 15;
    float4 a = accs[0][m][i], b = accs[1][m][i], cc = accs[2][m][i], dd = accs[3][m][i];
    float4 s = make_float4(a.x + b.x + cc.x + dd.x, a.y + b.y + cc.y + dd.y,
                           a.z + b.z + cc.z + dd.z, a.w + b.w + cc.w + dd.w);
    ((float4*)(ws + PA_OFF))[((size_t)(hb * 32 + c) * 8 + m) * 16 + i] = s;
  }
  if (tid < 8)
    ws[PD_OFF + (hb * NCHUNK + c) * 8 + tid] =
        dens[0][tid] + dens[1][tid] + dens[2][tid] + dens[3][tid];
}

// ---------------------------------------------------------------------------
// 5. pinv (Newton-Schulz, global max over all 512 colsums) fused with
//    k3v reduce + W2 = pinv @ (k3v/den).  One 512-thr block per head.
// ---------------------------------------------------------------------------
__global__ __launch_bounds__(512) void pinvw2_kernel(float* __restrict__ ws) {
  int hb = blockIdx.x, tid = threadIdx.x;
  __shared__ float k3vs[8][68];
  __shared__ float K[8][9], V[8][9], X[8][9], Y[8][9];
  __shared__ float smax;
  int m = tid >> 6, d = tid & 63;
  float s = 0.f, den = 0.f;
  for (int c = 0; c < NCHUNK; ++c) {
    s += ws[PA_OFF + (((size_t)hb * NCHUNK + c) * 8 + m) * 64 + d];
    den += ws[PD_OFF + (hb * NCHUNK + c) * 8 + m];
  }
  k3vs[m][d] = s / den;
  if (tid < 64) {
    float mx = 0.f;
    for (int t = 0; t < 8; ++t) mx = fmaxf(mx, ws[CS_OFF + t * 64 + tid]);
    for (int off = 32; off; off >>= 1) mx = fmaxf(mx, __shfl_xor(mx, off, 64));
    if (tid == 0) smax = mx;
  }
  int i = (tid >> 3) & 7, j = tid & 7;
  if (tid < 64) K[i][j] = ws[K2_OFF + hb * 64 + tid];
  __syncthreads();
  if (tid < 64) V[i][j] = K[j][i] * (1.f / smax);   // (1/max) * K^T
  __syncthreads();
  for (int it = 0; it < 6; ++it) {
    float x = 0.f;
    if (tid < 64) {
      for (int kk = 0; kk < 8; ++kk) x += K[i][kk] * V[kk][j];
      X[i][j] = x;
    }
    __syncthreads();
    float bm = 0.f;
    if (tid < 64) {
      for (int kk = 0; kk < 8; ++kk) bm += X[i][kk] * X[kk][j];
      bm = 7.f * x - bm;
      Y[i][j] = bm;
    }
    __syncthreads();
    float dm = 0.f;
    if (tid < 64) {
      for (int kk = 0; kk < 8; ++kk) dm += X[i][kk] * Y[kk][j];
      dm = 15.f * x - dm;
    }
    __syncthreads();
    if (tid < 64) Y[i][j] = dm;
    __syncthreads();
    float vd = 0.f;
    if (tid < 64) {
      for (int kk = 0; kk < 8; ++kk) vd += V[i][kk] * Y[kk][j];
      vd = 0.25f * (13.f * V[i][j] - vd);
    }
    __syncthreads();
    if (tid < 64) V[i][j] = vd;
    __syncthreads();
  }
  float o = 0.f;
#pragma unroll
  for (int jj = 0; jj < 8; ++jj) o += V[m][jj] * k3vs[jj][d];
  ws[W2_OFF + hb * 512 + tid] = o;
}

// ---------------------------------------------------------------------------
// 6. Output: one block per 128 tokens (2 x 64-token tiles, 2048 blocks).
//    klrow/w2s amortized over both tiles; tile-B loads issued during tile-A
//    staging; tile-B staging overlaps tile-A combine+store.
// ---------------------------------------------------------------------------
__global__ __launch_bounds__(256) void out_kernel(
    const float* __restrict__ q, float* __restrict__ out,
    const float* __restrict__ ws) {
  int hb = blockIdx.x >> 5, tt2 = blockIdx.x & 31;
  int tid = threadIdx.x;
  __shared__ float qt[64][68];
  __shared__ float w2s[8][68];
  __shared__ float pl[64][9];

  size_t base4 = ((size_t)hb * T_TOK + (size_t)tt2 * 128) * 16;
  const float4* q4 = (const float4*)q + base4;
  float4* o4 = (float4*)out + base4;

  float4 qqA[4], qqB[4];
#pragma unroll
  for (int it = 0; it < 4; ++it) qqA[it] = q4[it * 256 + tid];
  int m = tid & 7;
  float4 klrow[16];
#pragma unroll
  for (int d4 = 0; d4 < 16; ++d4)
    klrow[d4] = ((const float4*)(ws + KL_OFF))[hb * 128 + m * 16 + d4];
  if (tid < 128) {
    float4 y = ((const float4*)(ws + W2_OFF))[hb * 128 + tid];
    *(float4*)&w2s[tid >> 4][(tid & 15) * 4] = y;
  }
#pragma unroll
  for (int it = 0; it < 4; ++it) {
    int f4 = it * 256 + tid;
    *(float4*)&qt[f4 >> 4][(f4 & 15) * 4] = qqA[it];
  }
#pragma unroll
  for (int it = 0; it < 4; ++it) qqB[it] = q4[1024 + it * 256 + tid];
  __syncthreads();
  // dots A
#pragma unroll
  for (int rep = 0; rep < 2; ++rep) {
    int t = rep * 32 + (tid >> 3);
    const float4* qr = (const float4*)&qt[t][0];
    float dot = 0.f;
#pragma unroll
    for (int d4 = 0; d4 < 16; ++d4) {
      float4 a = qr[d4];
      dot += a.x * klrow[d4].x + a.y * klrow[d4].y +
             a.z * klrow[d4].z + a.w * klrow[d4].w;
    }
    pl[t][m] = __expf(dot * SCALE);
  }
  __syncthreads();
  // stage B (qt free: dots A done) + combine A + store A
#pragma unroll
  for (int it = 0; it < 4; ++it) {
    int f4 = it * 256 + tid;
    *(float4*)&qt[f4 >> 4][(f4 & 15) * 4] = qqB[it];
  }
#pragma unroll
  for (int i = 0; i < 4; ++i) {
    int t = i * 16 + (tid >> 4);
    int qd = tid & 15;
    float p0 = pl[t][0], p1 = pl[t][1], p2 = pl[t][2], p3 = pl[t][3];
    float p4 = pl[t][4], p5 = pl[t][5], p6 = pl[t][6], p7 = pl[t][7];
    float inv = 1.f / (p0 + p1 + p2 + p3 + p4 + p5 + p6 + p7);
    float4 acc = make_float4(0.f, 0.f, 0.f, 0.f);
    float pm[8] = {p0, p1, p2, p3, p4, p5, p6, p7};
#pragma unroll
    for (int m2 = 0; m2 < 8; ++m2) {
      float w = pm[m2] * inv;
      float4 wv = *(const float4*)&w2s[m2][qd * 4];
      acc.x += w * wv.x; acc.y += w * wv.y; acc.z += w * wv.z; acc.w += w * wv.w;
    }
    o4[i * 256 + tid] = acc;
  }
  __syncthreads();
  // dots B (pl free: combine A done)
#pragma unroll
  for (int rep = 0; rep < 2; ++rep) {
    int t = rep * 32 + (tid >> 3);
    const float4* qr = (const float4*)&qt[t][0];
    float dot = 0.f;
#pragma unroll
    for (int d4 = 0; d4 < 16; ++d4) {
      float4 a = qr[d4];
      dot += a.x * klrow[d4].x + a.y * klrow[d4].y +
             a.z * klrow[d4].z + a.w * klrow[d4].w;
    }
    pl[t][m] = __expf(dot * SCALE);
  }
  __syncthreads();
  // combine B + store B
#pragma unroll
  for (int i = 0; i < 4; ++i) {
    int t = i * 16 + (tid >> 4);
    int qd = tid & 15;
    float p0 = pl[t][0], p1 = pl[t][1], p2 = pl[t][2], p3 = pl[t][3];
    float p4 = pl[t][4], p5 = pl[t][5], p6 = pl[t][6], p7 = pl[t][7];
    float inv = 1.f / (p0 + p1 + p2 + p3 + p4 + p5 + p6 + p7);
    float4 acc = make_float4(0.f, 0.f, 0.f, 0.f);
    float pm[8] = {p0, p1, p2, p3, p4, p5, p6, p7};
#pragma unroll
    for (int m2 = 0; m2 < 8; ++m2) {
      float w = pm[m2] * inv;
      float4 wv = *(const float4*)&w2s[m2][qd * 4];
      acc.x += w * wv.x; acc.y += w * wv.y; acc.z += w * wv.z; acc.w += w * wv.w;
    }
    o4[1024 + i * 256 + tid] = acc;
  }
}

// ---------------------------------------------------------------------------
extern "C" void kernel_launch(void* const* d_in, const int* in_sizes, int n_in,
                              void* d_out, int out_size, void* d_ws, size_t ws_size,
                              hipStream_t stream) {
  const float* q = (const float*)d_in[0];
  const float* k = (const float*)d_in[1];
  const float* v = (const float*)d_in[2];
  float* out = (float*)d_out;
  float* ws = (float*)d_ws;

  qsum_kernel<<<512, 256, 0, stream>>>(q, ws);
  ppass_kernel<<<1024, 256, 0, stream>>>(k, ws);
  prepk_kernel<<<NHEADS, 512, 0, stream>>>(ws);
  vpass_kernel<<<NHEADS * NCHUNK, 256, 0, stream>>>(v, ws);
  pinvw2_kernel<<<NHEADS, 512, 0, stream>>>(ws);
  out_kernel<<<2048, 256, 0, stream>>>(q, out, ws);
}

// Round 8
// 88.761 us; speedup vs baseline: 1.2305x; 1.1459x over previous
//
#include <hip/hip_runtime.h>
#include <math.h>

#define T_TOK 4096
#define DD 64
#define NHEADS 64          // B*H = 4*16
#define SEG 512            // tokens per landmark segment
#define NCHUNK 32          // 128-token chunks per head (vpass granularity)
#define CHUNK 128
#define SCALE 0.125f

// workspace layout (in floats)
#define QL_OFF   0                      // [64][8][64]
#define KL_OFF   32768                  // [64][8][64]
#define K2_OFF   65536                  // [64][8][8]
#define CS_OFF   69632                  // [64][8]
#define KP_OFF   70144                  // [4096][64] k landmark partials (64-tok waves)
#define PA_OFF   70144                  // [64][32][8][64] (aliases KP: dead after prepk)
#define PD_OFF   1118720                // [64][32][8] denominators
#define W2_OFF   1135104                // [64][8][64] pinv @ k3v
#define P_OFF    1167872                // [64][4096][8] p values (8 MB)
// end = 3265024 floats ~= 13.06 MB (<= proven ws size)

#define WAVE_BAR() __builtin_amdgcn_wave_barrier()

// ---------------------------------------------------------------------------
// 1. q landmarks: one block per (head, landmark) 512-token segment (512 blocks).
//    Register double-buffered 8-load batches; writes q_l directly.
// ---------------------------------------------------------------------------
__global__ __launch_bounds__(256) void qsum_kernel(
    const float* __restrict__ q, float* __restrict__ ws) {
  int tid = threadIdx.x;
  const float4* q4 = (const float4*)q + (size_t)blockIdx.x * 8192;
  float4 b[2][8];
#pragma unroll
  for (int i = 0; i < 8; ++i) b[0][i] = q4[i * 256 + tid];
  float4 a = make_float4(0.f, 0.f, 0.f, 0.f);
#pragma unroll
  for (int j = 0; j < 4; ++j) {
    if (j < 3) {
#pragma unroll
      for (int i = 0; i < 8; ++i)
        b[(j + 1) & 1][i] = q4[(j + 1) * 2048 + i * 256 + tid];
    }
#pragma unroll
    for (int i = 0; i < 8; ++i) {
      float4 x = b[j & 1][i];
      a.x += x.x; a.y += x.y; a.z += x.z; a.w += x.w;
    }
  }
  __shared__ float4 red[16][17];
  red[tid >> 4][tid & 15] = a;
  __syncthreads();
  if (tid < 16) {
    float4 s = make_float4(0.f, 0.f, 0.f, 0.f);
#pragma unroll
    for (int g = 0; g < 16; ++g) {
      float4 r = red[g][tid];
      s.x += r.x; s.y += r.y; s.z += r.z; s.w += r.w;
    }
    const float inv = 1.f / (float)SEG;
    s.x *= inv; s.y *= inv; s.z *= inv; s.w *= inv;
    ((float4*)(ws + QL_OFF))[blockIdx.x * 16 + tid] = s;   // q_l directly
  }
}

// ---------------------------------------------------------------------------
// 2. ppass: barrier-free wave-private streaming.  Wave = 64 contiguous tokens
//    (4 x 16-token tiles in private LDS).  p[t][m]=exp(q_l[m].k[t]*scale) via
//    thread-local dots (8 thr/token, m = lane&7 fixed, q_l row in registers).
//    k landmark partials in registers, shfl-reduced at end.
// ---------------------------------------------------------------------------
__global__ __launch_bounds__(256) void ppass_kernel(
    const float* __restrict__ k, float* __restrict__ ws) {
  int tid = threadIdx.x;
  int w = tid >> 6, lane = tid & 63;
  int gw = blockIdx.x * 4 + w;            // 0..4095, 64 tokens each
  int hb = gw >> 6;
  __shared__ float kt_all[4][16][68];
  float (*kt)[68] = kt_all[w];

  int m = lane & 7;
  float4 qlrow[16];
#pragma unroll
  for (int d4 = 0; d4 < 16; ++d4)
    qlrow[d4] = ((const float4*)(ws + QL_OFF))[hb * 128 + m * 16 + d4];

  size_t tokbase = (size_t)gw * 64;
  const float4* k4 = (const float4*)k + tokbase * 16;
  float4 buf[2][4];
#pragma unroll
  for (int i = 0; i < 4; ++i) buf[0][i] = k4[i * 64 + lane];
  float4 ks = make_float4(0.f, 0.f, 0.f, 0.f);

#pragma unroll
  for (int tile = 0; tile < 4; ++tile) {
    int cur = tile & 1;
    if (tile < 3) {
#pragma unroll
      for (int i = 0; i < 4; ++i)
        buf[cur ^ 1][i] = k4[(tile + 1) * 256 + i * 64 + lane];
    }
#pragma unroll
    for (int i = 0; i < 4; ++i) {
      int f4 = i * 64 + lane;
      *(float4*)&kt[f4 >> 4][(f4 & 15) * 4] = buf[cur][i];
      ks.x += buf[cur][i].x; ks.y += buf[cur][i].y;
      ks.z += buf[cur][i].z; ks.w += buf[cur][i].w;
    }
    WAVE_BAR();
#pragma unroll
    for (int rep = 0; rep < 2; ++rep) {
      int t = rep * 8 + (lane >> 3);
      const float4* kr = (const float4*)&kt[t][0];
      float dp = 0.f;
#pragma unroll
      for (int d4 = 0; d4 < 16; ++d4) {
        float4 kv = kr[d4];
        dp += kv.x * qlrow[d4].x + kv.y * qlrow[d4].y +
              kv.z * qlrow[d4].z + kv.w * qlrow[d4].w;
      }
      // coalesced: lane = t*8+m exactly -> 256B contiguous per instruction
      ws[P_OFF + (tokbase + tile * 16 + t) * 8 + m] = __expf(dp * SCALE);
    }
    WAVE_BAR();
  }
  // reduce ksum over the 4 16-lane groups; lanes 0..15 hold 64-token sums
  ks.x += __shfl_xor(ks.x, 16, 64); ks.y += __shfl_xor(ks.y, 16, 64);
  ks.z += __shfl_xor(ks.z, 16, 64); ks.w += __shfl_xor(ks.w, 16, 64);
  ks.x += __shfl_xor(ks.x, 32, 64); ks.y += __shfl_xor(ks.y, 32, 64);
  ks.z += __shfl_xor(ks.z, 32, 64); ks.w += __shfl_xor(ks.w, 32, 64);
  if (lane < 16)
    ((float4*)(ws + KP_OFF))[gw * 16 + lane] = ks;
}

// ---------------------------------------------------------------------------
// 3. Reduce k partials -> k_l; kernel_2 softmax + column sums.
// ---------------------------------------------------------------------------
__global__ __launch_bounds__(512) void prepk_kernel(float* __restrict__ ws) {
  int hb = blockIdx.x, tid = threadIdx.x;
  __shared__ float qls[8][68];
  __shared__ float kls[8][68];
  __shared__ float ee[8][9];
  int m = tid >> 6, d = tid & 63;
  float s = 0.f;
#pragma unroll
  for (int j = 0; j < 8; ++j)
    s += ws[KP_OFF + (size_t)(hb * 64 + m * 8 + j) * 64 + d];
  s *= (1.f / (float)SEG);
  kls[m][d] = s;
  ws[KL_OFF + hb * 512 + tid] = s;
  qls[m][d] = ws[QL_OFF + hb * 512 + tid];
  __syncthreads();
  if (tid < 64) {
    int i = tid >> 3, j = tid & 7;
    float dot = 0.f;
#pragma unroll
    for (int dd = 0; dd < 64; ++dd) dot += qls[i][dd] * kls[j][dd];
    ee[i][j] = __expf(dot * SCALE);   // logits tiny: shift-free softmax safe
  }
  __syncthreads();
  if (tid < 64) {
    int i = tid >> 3, j = tid & 7;
    float ssum = 0.f;
#pragma unroll
    for (int jj = 0; jj < 8; ++jj) ssum += ee[i][jj];
    ws[K2_OFF + hb * 64 + tid] = ee[i][j] / ssum;
  }
  if (tid < 8) {
    float cs = 0.f;
    for (int ii = 0; ii < 8; ++ii) {
      float ssum = 0.f;
#pragma unroll
      for (int jj = 0; jj < 8; ++jj) ssum += ee[ii][jj];
      cs += ee[ii][tid] / ssum;
    }
    ws[CS_OFF + hb * 8 + tid] = cs;
  }
}

// ---------------------------------------------------------------------------
// 4. vpass: read v (hoisted loads) + p; accumulate k3v partials AND the
//    per-chunk denominators.
// ---------------------------------------------------------------------------
__global__ __launch_bounds__(256) void vpass_kernel(
    const float* __restrict__ v, float* __restrict__ ws) {
  int tid = threadIdx.x;
  int w = tid >> 6, lane = tid & 63, g = lane >> 4;
  int hb = blockIdx.x >> 5, c = blockIdx.x & 31;

  size_t tokbase = (size_t)hb * T_TOK + (size_t)c * CHUNK + (size_t)w * 32;
  float4 pf = ((const float4*)(ws + P_OFF))[tokbase * 2 + lane];
  const float4* v4 = (const float4*)v + tokbase * 16;
  float4 vv[8];
#pragma unroll
  for (int it = 0; it < 8; ++it) vv[it] = v4[it * 64 + lane];

  __shared__ float plds[4][260];
  *(float4*)&plds[w][lane * 4] = pf;
  WAVE_BAR();

  float4 acc[8];
#pragma unroll
  for (int m = 0; m < 8; ++m) acc[m] = make_float4(0.f, 0.f, 0.f, 0.f);

#pragma unroll
  for (int it = 0; it < 8; ++it) {
    int t = it * 4 + g;
    float4 pa = *(const float4*)&plds[w][t * 8];
    float4 pb = *(const float4*)&plds[w][t * 8 + 4];
    acc[0].x += pa.x * vv[it].x; acc[0].y += pa.x * vv[it].y; acc[0].z += pa.x * vv[it].z; acc[0].w += pa.x * vv[it].w;
    acc[1].x += pa.y * vv[it].x; acc[1].y += pa.y * vv[it].y; acc[1].z += pa.y * vv[it].z; acc[1].w += pa.y * vv[it].w;
    acc[2].x += pa.z * vv[it].x; acc[2].y += pa.z * vv[it].y; acc[2].z += pa.z * vv[it].z; acc[2].w += pa.z * vv[it].w;
    acc[3].x += pa.w * vv[it].x; acc[3].y += pa.w * vv[it].y; acc[3].z += pa.w * vv[it].z; acc[3].w += pa.w * vv[it].w;
    acc[4].x += pb.x * vv[it].x; acc[4].y += pb.x * vv[it].y; acc[4].z += pb.x * vv[it].z; acc[4].w += pb.x * vv[it].w;
    acc[5].x += pb.y * vv[it].x; acc[5].y += pb.y * vv[it].y; acc[5].z += pb.y * vv[it].z; acc[5].w += pb.y * vv[it].w;
    acc[6].x += pb.z * vv[it].x; acc[6].y += pb.z * vv[it].y; acc[6].z += pb.z * vv[it].z; acc[6].w += pb.z * vv[it].w;
    acc[7].x += pb.w * vv[it].x; acc[7].y += pb.w * vv[it].y; acc[7].z += pb.w * vv[it].z; acc[7].w += pb.w * vv[it].w;
  }
#pragma unroll
  for (int m = 0; m < 8; ++m) {
#pragma unroll
    for (int s = 16; s <= 32; s <<= 1) {
      acc[m].x += __shfl_xor(acc[m].x, s, 64);
      acc[m].y += __shfl_xor(acc[m].y, s, 64);
      acc[m].z += __shfl_xor(acc[m].z, s, 64);
      acc[m].w += __shfl_xor(acc[m].w, s, 64);
    }
  }
  __shared__ float4 accs[4][8][17];
  __shared__ float dens[4][8];
  if (lane < 16) {
#pragma unroll
    for (int m = 0; m < 8; ++m) accs[w][m][lane] = acc[m];
  }
  if (lane < 8) {
    float dsum = 0.f;
#pragma unroll
    for (int t = 0; t < 32; ++t) dsum += plds[w][t * 8 + lane];
    dens[w][lane] = dsum;
  }
  __syncthreads();
  if (tid < 128) {
    int m = tid >> 4, i = tid & 15;
    float4 a = accs[0][m][i], b = accs[1][m][i], cc = accs[2][m][i], dd = accs[3][m][i];
    float4 s = make_float4(a.x + b.x + cc.x + dd.x, a.y + b.y + cc.y + dd.y,
                           a.z + b.z + cc.z + dd.z, a.w + b.w + cc.w + dd.w);
    ((float4*)(ws + PA_OFF))[((size_t)(hb * 32 + c) * 8 + m) * 16 + i] = s;
  }
  if (tid < 8)
    ws[PD_OFF + (hb * NCHUNK + c) * 8 + tid] =
        dens[0][tid] + dens[1][tid] + dens[2][tid] + dens[3][tid];
}

// ---------------------------------------------------------------------------
// 5. pinv (Newton-Schulz, global max over all 512 colsums) fused with
//    k3v reduce + W2 = pinv @ (k3v/den).  One 512-thr block per head.
// ---------------------------------------------------------------------------
__global__ __launch_bounds__(512) void pinvw2_kernel(float* __restrict__ ws) {
  int hb = blockIdx.x, tid = threadIdx.x;
  __shared__ float k3vs[8][68];
  __shared__ float K[8][9], V[8][9], X[8][9], Y[8][9];
  __shared__ float smax;
  int m = tid >> 6, d = tid & 63;
  float s = 0.f, den = 0.f;
  for (int c = 0; c < NCHUNK; ++c) {
    s += ws[PA_OFF + (((size_t)hb * NCHUNK + c) * 8 + m) * 64 + d];
    den += ws[PD_OFF + (hb * NCHUNK + c) * 8 + m];
  }
  k3vs[m][d] = s / den;
  if (tid < 64) {
    float mx = 0.f;
    for (int t = 0; t < 8; ++t) mx = fmaxf(mx, ws[CS_OFF + t * 64 + tid]);
    for (int off = 32; off; off >>= 1) mx = fmaxf(mx, __shfl_xor(mx, off, 64));
    if (tid == 0) smax = mx;
  }
  int i = (tid >> 3) & 7, j = tid & 7;
  if (tid < 64) K[i][j] = ws[K2_OFF + hb * 64 + tid];
  __syncthreads();
  if (tid < 64) V[i][j] = K[j][i] * (1.f / smax);   // (1/max) * K^T
  __syncthreads();
  for (int it = 0; it < 6; ++it) {
    float x = 0.f;
    if (tid < 64) {
      for (int kk = 0; kk < 8; ++kk) x += K[i][kk] * V[kk][j];
      X[i][j] = x;
    }
    __syncthreads();
    float bm = 0.f;
    if (tid < 64) {
      for (int kk = 0; kk < 8; ++kk) bm += X[i][kk] * X[kk][j];
      bm = 7.f * x - bm;
      Y[i][j] = bm;
    }
    __syncthreads();
    float dm = 0.f;
    if (tid < 64) {
      for (int kk = 0; kk < 8; ++kk) dm += X[i][kk] * Y[kk][j];
      dm = 15.f * x - dm;
    }
    __syncthreads();
    if (tid < 64) Y[i][j] = dm;
    __syncthreads();
    float vd = 0.f;
    if (tid < 64) {
      for (int kk = 0; kk < 8; ++kk) vd += V[i][kk] * Y[kk][j];
      vd = 0.25f * (13.f * V[i][j] - vd);
    }
    __syncthreads();
    if (tid < 64) V[i][j] = vd;
    __syncthreads();
  }
  float o = 0.f;
#pragma unroll
  for (int jj = 0; jj < 8; ++jj) o += V[m][jj] * k3vs[jj][d];
  ws[W2_OFF + hb * 512 + tid] = o;
}

// ---------------------------------------------------------------------------
// 6. Output: barrier-free wave-private streaming.  Wave = 64 contiguous
//    tokens (4 x 16-token tiles).  klrow in VGPRs; W2 in private LDS.
//    p = exp(q.k_l*scale); out = (p/Σp) @ W2.  1 KB coalesced stores.
// ---------------------------------------------------------------------------
__global__ __launch_bounds__(256) void out_kernel(
    const float* __restrict__ q, float* __restrict__ out,
    const float* __restrict__ ws) {
  int tid = threadIdx.x;
  int w = tid >> 6, lane = tid & 63;
  int gw = blockIdx.x * 4 + w;            // 0..4095, 64 tokens each
  int hb = gw >> 6;
  __shared__ float qt_all[4][16][68];
  __shared__ float pl_all[4][16][9];
  __shared__ float w2_all[4][8][68];
  float (*qt)[68] = qt_all[w];
  float (*pl)[9]  = pl_all[w];
  float (*w2)[68] = w2_all[w];

  int m = lane & 7;
  float4 klrow[16];
#pragma unroll
  for (int d4 = 0; d4 < 16; ++d4)
    klrow[d4] = ((const float4*)(ws + KL_OFF))[hb * 128 + m * 16 + d4];
#pragma unroll
  for (int i = 0; i < 2; ++i) {
    int f4 = i * 64 + lane;
    float4 y = ((const float4*)(ws + W2_OFF))[hb * 128 + f4];
    *(float4*)&w2[f4 >> 4][(f4 & 15) * 4] = y;
  }

  size_t base4 = (size_t)gw * 1024;       // 64 tokens x 16 float4
  const float4* q4 = (const float4*)q + base4;
  float4* o4 = (float4*)out + base4;
  float4 buf[2][4];
#pragma unroll
  for (int i = 0; i < 4; ++i) buf[0][i] = q4[i * 64 + lane];

#pragma unroll
  for (int tile = 0; tile < 4; ++tile) {
    int cur = tile & 1;
    if (tile < 3) {
#pragma unroll
      for (int i = 0; i < 4; ++i)
        buf[cur ^ 1][i] = q4[(tile + 1) * 256 + i * 64 + lane];
    }
#pragma unroll
    for (int i = 0; i < 4; ++i) {
      int f4 = i * 64 + lane;
      *(float4*)&qt[f4 >> 4][(f4 & 15) * 4] = buf[cur][i];
    }
    WAVE_BAR();
#pragma unroll
    for (int rep = 0; rep < 2; ++rep) {
      int t = rep * 8 + (lane >> 3);
      const float4* qr = (const float4*)&qt[t][0];
      float dot = 0.f;
#pragma unroll
      for (int d4 = 0; d4 < 16; ++d4) {
        float4 a = qr[d4];
        dot += a.x * klrow[d4].x + a.y * klrow[d4].y +
               a.z * klrow[d4].z + a.w * klrow[d4].w;
      }
      pl[t][m] = __expf(dot * SCALE);     // logits tiny: no max needed
    }
    WAVE_BAR();
#pragma unroll
    for (int i = 0; i < 4; ++i) {
      int t = i * 4 + (lane >> 4);
      int qd = lane & 15;
      float p0 = pl[t][0], p1 = pl[t][1], p2 = pl[t][2], p3 = pl[t][3];
      float p4 = pl[t][4], p5 = pl[t][5], p6 = pl[t][6], p7 = pl[t][7];
      float inv = 1.f / (p0 + p1 + p2 + p3 + p4 + p5 + p6 + p7);
      float4 acc = make_float4(0.f, 0.f, 0.f, 0.f);
      float pm[8] = {p0, p1, p2, p3, p4, p5, p6, p7};
#pragma unroll
      for (int m2 = 0; m2 < 8; ++m2) {
        float wgt = pm[m2] * inv;
        float4 wv = *(const float4*)&w2[m2][qd * 4];
        acc.x += wgt * wv.x; acc.y += wgt * wv.y;
        acc.z += wgt * wv.z; acc.w += wgt * wv.w;
      }
      o4[tile * 256 + i * 64 + lane] = acc;   // 1 KB coalesced store
    }
    WAVE_BAR();
  }
}

// ---------------------------------------------------------------------------
extern "C" void kernel_launch(void* const* d_in, const int* in_sizes, int n_in,
                              void* d_out, int out_size, void* d_ws, size_t ws_size,
                              hipStream_t stream) {
  const float* q = (const float*)d_in[0];
  const float* k = (const float*)d_in[1];
  const float* v = (const float*)d_in[2];
  float* out = (float*)d_out;
  float* ws = (float*)d_ws;

  qsum_kernel<<<512, 256, 0, stream>>>(q, ws);
  ppass_kernel<<<1024, 256, 0, stream>>>(k, ws);
  prepk_kernel<<<NHEADS, 512, 0, stream>>>(ws);
  vpass_kernel<<<NHEADS * NCHUNK, 256, 0, stream>>>(v, ws);
  pinvw2_kernel<<<NHEADS, 512, 0, stream>>>(ws);
  out_kernel<<<1024, 256, 0, stream>>>(q, out, ws);
}